// Round 6
// baseline (103.745 us; speedup 1.0000x reference)
//
#include <hip/hip_runtime.h>
#include <math.h>

// QASA layer: out = circuit(x @ W_in.T + b_in, q_weights) @ W_out.T + b_out
// 8 qubits -> 256 complex amps. State idx = lane*4 + r: idx bits [7:2] =
// lane bits [5:0], bits [1:0] = reg. Wire i acts on idx bit 7-i.
//
// Round 6: latency scheduling (structure of round 5 kept: 8 rows/block,
// 2 rows/wave circuit ILP, cooperative GEMV phases).
//  - W_in slices loaded ONCE per wave (round 5 reloaded per pass).
//  - Phase-1 staged so peak in-flight fits the 128-VGPR cap; g=1 x-loads
//    issue before g=0's DPP-reduce (reduce covers load latency).
//  - Phase-4 operands (W_out slice + bias) PREFETCHED right after the first
//    barrier, before the circuit: ~900 cyc of load latency hidden under the
//    circuit dependency chain.
//  - b_in gather hoisted; phase-1 accumulation packed (v_pk_fma_f32).
// Circuit algebra unchanged (CNOT ladders eliminated via F=I+S conjugation;
// layer 0 + embedding absorbed into product factors; f32x2 packed math).

typedef float f32x2 __attribute__((ext_vector_type(2)));

__device__ __forceinline__ int f2i(float v) { return __float_as_int(v); }
__device__ __forceinline__ float i2f(int v) { return __int_as_float(v); }

template <int CTRL>
__device__ __forceinline__ float dppf(float v) {
    return i2f(__builtin_amdgcn_update_dpp(0, f2i(v), CTRL, 0xF, 0xF, true));
}

// generalized xor-mask cross-lane: DPP where possible, ds_swizzle <32, shfl >=32
template <int ML>
__device__ __forceinline__ float gshm(float v) {
    static_assert(ML > 0 && ML < 64, "lane mask");
    if constexpr (ML == 1)      return dppf<0xB1>(v);        // quad_perm [1,0,3,2]
    else if constexpr (ML == 2) return dppf<0x4E>(v);        // quad_perm [2,3,0,1]
    else if constexpr (ML == 3) return dppf<0x1B>(v);        // quad_perm [3,2,1,0]
    else if constexpr (ML == 8) return dppf<0x128>(v);       // row_ror:8 == xor8 in 16
    else if constexpr (ML < 32) return i2f(__builtin_amdgcn_ds_swizzle(f2i(v), 0x1F | (ML << 10)));
    else                        return __shfl_xor(v, ML, 64);
}

template <int L>
__device__ __forceinline__ float rdlane(float v) {
    return i2f(__builtin_amdgcn_readlane(f2i(v), L));
}

// Generalized gate on packed state: RX(th1) about axis (lane-mask ML,
// reg-mask MR), then RZ(th2) with sign = parity(lane&ZL)^parity(r&ZR).
template <int ML, int MR, int ZL, int ZR>
__device__ __forceinline__ void ggate(f32x2& reA, f32x2& reB, f32x2& imA, f32x2& imB,
                                      float c1, float s1, float c2, float s2,
                                      int lane) {
    // ---- partner fetch: reg-swizzle by MR, then lane-xor by ML ----
    f32x2 sReA, sReB, sImA, sImB;
    if constexpr (MR == 0)      { sReA = reA;    sReB = reB;    sImA = imA;    sImB = imB; }
    else if constexpr (MR == 1) { sReA = reA.yx; sReB = reB.yx; sImA = imA.yx; sImB = imB.yx; }
    else if constexpr (MR == 2) { sReA = reB;    sReB = reA;    sImA = imB;    sImB = imA; }
    else                        { sReA = reB.yx; sReB = reA.yx; sImA = imB.yx; sImB = imA.yx; }
    f32x2 pReA, pReB, pImA, pImB;
    if constexpr (ML != 0) {
        pReA.x = gshm<ML>(sReA.x); pReA.y = gshm<ML>(sReA.y);
        pReB.x = gshm<ML>(sReB.x); pReB.y = gshm<ML>(sReB.y);
        pImA.x = gshm<ML>(sImA.x); pImA.y = gshm<ML>(sImA.y);
        pImB.x = gshm<ML>(sImB.x); pImB.y = gshm<ML>(sImB.y);
    } else { pReA = sReA; pReB = sReB; pImA = sImA; pImB = sImB; }
    // ---- RX ----
    f32x2 nReA = c1 * reA + s1 * pImA;
    f32x2 nReB = c1 * reB + s1 * pImB;
    f32x2 nImA = c1 * imA - s1 * pReA;
    f32x2 nImB = c1 * imB - s1 * pReB;
    // ---- RZ: ss_r = sigma(r) * base, base = parity(lane&ZL) ? s2 : -s2 ----
    float base;
    if constexpr (ZL == 0) base = -s2;
    else                   base = (__popc(lane & ZL) & 1) ? s2 : -s2;
    constexpr bool N1 = (ZR & 1) != 0;                       // sigma(1)
    constexpr bool N2 = ((ZR >> 1) & 1) != 0;                // sigma(2)
    constexpr bool N3 = (((ZR & 1) ^ ((ZR >> 1) & 1)) != 0); // sigma(3)
    f32x2 ssA = { base, N1 ? -base : base };
    f32x2 ssB = { N2 ? -base : base, N3 ? -base : base };
    f32x2 tA = c2 * nReA - ssA * nImA;
    f32x2 tB = c2 * nReB - ssB * nImB;
    imA = c2 * nImA + ssA * nReA;
    imB = c2 * nImB + ssB * nReB;
    reA = tA;
    reB = tB;
}

// Product expansion: state after layer 0 from per-wire factors held in
// lanes BASE+{0,1,2,3,8,9,10,11}.
template <int BASE>
__device__ __forceinline__ void expand_state(float ur2, float ui2, float vr2, float vi2,
                                             int lane,
                                             f32x2& reA, f32x2& reB, f32x2& imA, f32x2& imB) {
    float Pr, Pi;
    {   // wire 0 (lane bit 5), factor in lane BASE
        float fur = rdlane<BASE + 0>(ur2), fui = rdlane<BASE + 0>(ui2);
        float fvr = rdlane<BASE + 0>(vr2), fvi = rdlane<BASE + 0>(vi2);
        bool b = (lane >> 5) & 1;
        Pr = b ? fvr : fur;
        Pi = b ? fvi : fui;
    }
#define PMUL(W_, L_) { \
        float fur = rdlane<BASE + L_>(ur2), fui = rdlane<BASE + L_>(ui2); \
        float fvr = rdlane<BASE + L_>(vr2), fvi = rdlane<BASE + L_>(vi2); \
        bool b = (lane >> (5 - (W_))) & 1; \
        float fr = b ? fvr : fur, fi = b ? fvi : fui; \
        float tr = Pr * fr - Pi * fi; \
        Pi = Pr * fi + Pi * fr; \
        Pr = tr; }
    PMUL(1, 1) PMUL(2, 2) PMUL(3, 3) PMUL(4, 8) PMUL(5, 9)
#undef PMUL
    {   // wires 6 (reg bit1, lane BASE+10) and 7 (reg bit0, lane BASE+11)
        float u6r = rdlane<BASE + 10>(ur2), u6i = rdlane<BASE + 10>(ui2);
        float v6r = rdlane<BASE + 10>(vr2), v6i = rdlane<BASE + 10>(vi2);
        float u7r = rdlane<BASE + 11>(ur2), u7i = rdlane<BASE + 11>(ui2);
        float v7r = rdlane<BASE + 11>(vr2), v7i = rdlane<BASE + 11>(vi2);
        float rr[4], ii[4];
#pragma unroll
        for (int r = 0; r < 4; ++r) {
            float g6r_ = (r & 2) ? v6r : u6r, g6i_ = (r & 2) ? v6i : u6i;
            float g7r_ = (r & 1) ? v7r : u7r, g7i_ = (r & 1) ? v7i : u7i;
            float fr = g6r_ * g7r_ - g6i_ * g7i_;
            float fi = g6r_ * g7i_ + g6i_ * g7r_;
            rr[r] = Pr * fr - Pi * fi;
            ii[r] = Pr * fi + Pi * fr;
        }
        reA = (f32x2){ rr[0], rr[1] };  reB = (f32x2){ rr[2], rr[3] };
        imA = (f32x2){ ii[0], ii[1] };  imB = (f32x2){ ii[2], ii[3] };
    }
}

__global__ void __launch_bounds__(256, 4) qasa_kernel(
    const float* __restrict__ x, const float* __restrict__ W_in,
    const float* __restrict__ b_in, const float* __restrict__ qw,
    const float* __restrict__ W_out, const float* __restrict__ b_out,
    float* __restrict__ out)
{
    const int tid = threadIdx.x;
    const int lane = tid & 63;
    const int w = tid >> 6;                       // wave id in block
    const int block8 = blockIdx.x * 8;

    __shared__ float ang[64];                     // [q][8 rows]
    __shared__ float evs[8][8] __attribute__((aligned(16)));  // [row][ev]

    // per-wave layer trig, lane-indexed in VGPRs (qw has exactly 64 entries)
    float vc, vs;
    __sincosf(0.5f * qw[lane], &vs, &vc);

    const int b0 = lane & 1, b1 = (lane >> 1) & 1, b3 = (lane >> 3) & 1;
    const int qofl = b0 | (b1 << 1) | (b3 << 2);  // qubit index held by this lane
    const float binq = b_in[qofl];                // hoisted gather (8 values)

    // ---- phase 1 (cooperative): wave w computes angles for q = 2w, 2w+1
    //      over all 8 rows. W_in slices loaded ONCE; x staged per 4-row pass;
    //      pass-1 loads issue before pass-0's reduce (reduce hides latency).
    {
        const float4* w4 = (const float4*)W_in;
        float4 wv0[4], wv1[4];
#pragma unroll
        for (int k = 0; k < 4; ++k) {
            wv0[k] = w4[(2 * w) * 256 + lane + 64 * k];
            wv1[k] = w4[(2 * w + 1) * 256 + lane + 64 * k];
        }
        const float4* xr0 = (const float4*)(x + (size_t)block8 * 1024);
        const float4* xr1 = (const float4*)(x + (size_t)(block8 + 4) * 1024);

        // ---- pass 0 loads (rows 0-3) ----
        float4 xv[4][4];
#pragma unroll
        for (int r = 0; r < 4; ++r)
#pragma unroll
            for (int k = 0; k < 4; ++k)
                xv[r][k] = xr0[r * 256 + lane + 64 * k];

        // ---- pass 0 compute (packed) ----
        f32x2 acc2[8];
#pragma unroll
        for (int j = 0; j < 8; ++j) acc2[j] = (f32x2){0.f, 0.f};
#pragma unroll
        for (int k = 0; k < 4; ++k)
#pragma unroll
            for (int r = 0; r < 4; ++r) {
                float4 xvv = xv[r][k];
                acc2[r]     += (f32x2){xvv.x, xvv.y} * (f32x2){wv0[k].x, wv0[k].y}
                             + (f32x2){xvv.z, xvv.w} * (f32x2){wv0[k].z, wv0[k].w};
                acc2[4 + r] += (f32x2){xvv.x, xvv.y} * (f32x2){wv1[k].x, wv1[k].y}
                             + (f32x2){xvv.z, xvv.w} * (f32x2){wv1[k].z, wv1[k].w};
            }

        // ---- pass 1 loads issued NOW (xv regs free; latency hidden by reduce) ----
        float4 yv[4][4];
#pragma unroll
        for (int r = 0; r < 4; ++r)
#pragma unroll
            for (int k = 0; k < 4; ++k)
                yv[r][k] = xr1[r * 256 + lane + 64 * k];

        // ---- pass 0 reduce + write ----
        {
            float acc[8];
#pragma unroll
            for (int j = 0; j < 8; ++j) {
                acc[j] = acc2[j].x + acc2[j].y;
                acc[j] += dppf<0xB1>(acc[j]);
                acc[j] += dppf<0x4E>(acc[j]);
                acc[j] += dppf<0x128>(acc[j]);
            }
            float t01 = b0 ? acc[1] : acc[0];
            float t23 = b0 ? acc[3] : acc[2];
            float t45 = b0 ? acc[5] : acc[4];
            float t67 = b0 ? acc[7] : acc[6];
            float ta = b1 ? t23 : t01;
            float tb = b1 ? t67 : t45;
            float S = b3 ? tb : ta;
            S += gshm<4>(S); S += gshm<16>(S); S += gshm<32>(S);
            if ((lane & 52) == 0)
                ang[(2 * w + ((lane >> 3) & 1)) * 8 + (lane & 3)] = S;
        }

        // ---- pass 1 compute + reduce + write ----
        {
            f32x2 bcc2[8];
#pragma unroll
            for (int j = 0; j < 8; ++j) bcc2[j] = (f32x2){0.f, 0.f};
#pragma unroll
            for (int k = 0; k < 4; ++k)
#pragma unroll
                for (int r = 0; r < 4; ++r) {
                    float4 xvv = yv[r][k];
                    bcc2[r]     += (f32x2){xvv.x, xvv.y} * (f32x2){wv0[k].x, wv0[k].y}
                                 + (f32x2){xvv.z, xvv.w} * (f32x2){wv0[k].z, wv0[k].w};
                    bcc2[4 + r] += (f32x2){xvv.x, xvv.y} * (f32x2){wv1[k].x, wv1[k].y}
                                 + (f32x2){xvv.z, xvv.w} * (f32x2){wv1[k].z, wv1[k].w};
                }
            float acc[8];
#pragma unroll
            for (int j = 0; j < 8; ++j) {
                acc[j] = bcc2[j].x + bcc2[j].y;
                acc[j] += dppf<0xB1>(acc[j]);
                acc[j] += dppf<0x4E>(acc[j]);
                acc[j] += dppf<0x128>(acc[j]);
            }
            float t01 = b0 ? acc[1] : acc[0];
            float t23 = b0 ? acc[3] : acc[2];
            float t45 = b0 ? acc[5] : acc[4];
            float t67 = b0 ? acc[7] : acc[6];
            float ta = b1 ? t23 : t01;
            float tb = b1 ? t67 : t45;
            float S = b3 ? tb : ta;
            S += gshm<4>(S); S += gshm<16>(S); S += gshm<32>(S);
            if ((lane & 52) == 0)
                ang[(2 * w + ((lane >> 3) & 1)) * 8 + 4 + (lane & 3)] = S;
        }
    }
    __syncthreads();

    // ---- phase-4 operand PREFETCH (latency hides under the circuit) ----
    const int c4 = (w << 6) + lane;     // float4-col index owned by this wave
    const float4* wo = (const float4*)W_out;
    float4 wa[4], wb[4];
#pragma unroll
    for (int c = 0; c < 4; ++c) {
        wa[c] = wo[2 * (4 * c4 + c)];
        wb[c] = wo[2 * (4 * c4 + c) + 1];
    }
    float4 bias = ((const float4*)b_out)[c4];

    // ---- phase 2a: per-wire factors for BOTH rows in one stream ----
    // lanes 0-11: row w (group A); lanes 16-27: row w+4 (group B)
    const int rsel = w + ((lane >> 2) & 4);       // row for this lane's group
    float A = ang[qofl * 8 + rsel] + binq;
    float ca, sa;
    __sincosf(0.5f * A, &sa, &ca);
    // embedding part: u = (ca^2, -ca*sa), v = (sa^2, -ca*sa)
    float ur = ca * ca, ui = -ca * sa, vr = sa * sa, vi = ui;
    const int a1 = 4 * qofl, a2 = 4 * (qofl + 8);
    float cx = i2f(__builtin_amdgcn_ds_bpermute(a1, f2i(vc)));
    float sx = i2f(__builtin_amdgcn_ds_bpermute(a1, f2i(vs)));
    float cz = i2f(__builtin_amdgcn_ds_bpermute(a2, f2i(vc)));
    float sz = i2f(__builtin_amdgcn_ds_bpermute(a2, f2i(vs)));
    // RX(qx): u' = cx*u - i sx*v ; v' = cx*v - i sx*u
    float ur1 = cx * ur + sx * vi, ui1 = cx * ui - sx * vr;
    float vr1 = cx * vr + sx * ui, vi1 = cx * vi - sx * ur;
    // RZ(qz): u'' = (cz - i sz) u' ; v'' = (cz + i sz) v'
    float ur2 = cz * ur1 + sz * ui1, ui2 = cz * ui1 - sz * ur1;
    float vr2 = cz * vr1 - sz * vi1, vi2 = cz * vi1 + sz * vr1;

    // ---- phase 2b-init: product expansion for both rows ----
    f32x2 reA0, reB0, imA0, imB0;   // row w
    f32x2 reA1, reB1, imA1, imB1;   // row w+4
    expand_state<0>(ur2, ui2, vr2, vi2, lane, reA0, reB0, imA0, imB0);
    expand_state<16>(ur2, ui2, vr2, vi2, lane, reA1, reB1, imA1, imB1);

    // ---- phase 2b: layers 1-3 on both rows (independent ILP-2 chains) ----
    // qw[l][0][i] -> lane 16l+i (RX), qw[l][1][i] -> lane 16l+8+i (RZ)
#define GG(Lx, W_, ML_, MR_, ZL_, ZR_) { \
    float c1 = rdlane<16 * (Lx) + (W_)>(vc), s1 = rdlane<16 * (Lx) + (W_)>(vs); \
    float c2 = rdlane<16 * (Lx) + 8 + (W_)>(vc), s2 = rdlane<16 * (Lx) + 8 + (W_)>(vs); \
    ggate<ML_, MR_, ZL_, ZR_>(reA0, reB0, imA0, imB0, c1, s1, c2, s2, lane); \
    ggate<ML_, MR_, ZL_, ZR_>(reA1, reB1, imA1, imB1, c1, s1, c2, s2, lane); }

    // layer 2 (a=1): axis F e_k = {k,k-1}; RZ rows of F^-1 = {k..7}
    GG(1,0, 48,0, 32,0)  GG(1,1, 24,0, 48,0)  GG(1,2, 12,0, 56,0) GG(1,3, 6,0, 60,0)
    GG(1,4, 3,0, 62,0)   GG(1,5, 1,2, 63,0)   GG(1,6, 0,3, 63,2)  GG(1,7, 0,1, 63,3)
    // layer 3 (a=2): axis {k,k-2}; RZ rows of F^-2 = {k,k+2,k+4,k+6}
    GG(2,0, 40,0, 32,0)  GG(2,1, 20,0, 16,0)  GG(2,2, 10,0, 40,0) GG(2,3, 5,0, 20,0)
    GG(2,4, 2,2, 42,0)   GG(2,5, 1,1, 21,0)   GG(2,6, 0,2, 42,2)  GG(2,7, 0,1, 21,1)
    // layer 4 (a=3): axis {k,k-1,k-2,k-3}; RZ rows of F^-3 = {k,k+1,k+4,k+5}
    GG(3,0, 60,0, 32,0)  GG(3,1, 30,0, 48,0)  GG(3,2, 15,0, 24,0) GG(3,3, 7,2, 12,0)
    GG(3,4, 3,3, 38,0)   GG(3,5, 1,3, 51,0)   GG(3,6, 0,3, 25,2)  GG(3,7, 0,1, 12,3)
#undef GG

    // ---- phase 3: expvals for both rows (F^-4-absorbed masks) ----
#define BUTTERFLY(reA, reB, imA, imB, vq0, vq1, vq2) \
    float p0 = reA.x * reA.x + imA.x * imA.x; \
    float p1 = reA.y * reA.y + imA.y * imA.y; \
    float p2 = reB.x * reB.x + imB.x * imB.x; \
    float p3 = reB.y * reB.y + imB.y * imB.y; \
    float vq0 = (p0 + p1) + (p2 + p3); \
    float vq2 = (p0 + p1) - (p2 + p3); \
    float vq1 = (p0 + p2) - (p1 + p3); \
    { float u = dppf<0xB1>(vq0);  vq0 = (lane & 1)  ? (u - vq0) : (vq0 + u); } \
    { float u = dppf<0x4E>(vq0);  vq0 = (lane & 2)  ? (u - vq0) : (vq0 + u); } \
    { float u = dppf<0x128>(vq0); vq0 = (lane & 8)  ? (u - vq0) : (vq0 + u); } \
    { float u = gshm<4>(vq0);     vq0 = (lane & 4)  ? (u - vq0) : (vq0 + u); } \
    { float u = gshm<16>(vq0);    vq0 = (lane & 16) ? (u - vq0) : (vq0 + u); } \
    { float u = gshm<32>(vq0);    vq0 = (lane & 32) ? (u - vq0) : (vq0 + u); } \
    vq2 += dppf<0xB1>(vq2); \
    vq2 += dppf<0x4E>(vq2); \
    { float u = dppf<0x128>(vq2); vq2 = (lane & 8) ? (u - vq2) : (vq2 + u); } \
    vq2 += gshm<4>(vq2); vq2 += gshm<16>(vq2); vq2 += gshm<32>(vq2); \
    vq1 += dppf<0xB1>(vq1); \
    vq1 += dppf<0x4E>(vq1); \
    vq1 += dppf<0x128>(vq1); \
    { float u = gshm<4>(vq1); vq1 = (lane & 4) ? (u - vq1) : (vq1 + u); } \
    vq1 += gshm<16>(vq1); vq1 += gshm<32>(vq1);

    float v0, v1, q1A, q1B, q2A, q2B;
    { BUTTERFLY(reA0, reB0, imA0, imB0, vv, w1, w2) v0 = vv; q1A = w1; q2A = w2; }
    { BUTTERFLY(reA1, reB1, imA1, imB1, vv, w1, w2) v1 = vv; q1B = w1; q2B = w2; }
#undef BUTTERFLY

    // write EVs to LDS directly from their holder lanes (both rows)
    {
        const unsigned long long wrmask = 0x0000000500030110ULL; // lanes 4,8,16,17,32,34
        if ((wrmask >> lane) & 1) {
            int k = 6 - __ffs(lane);        // 32->0,16->1,8->2,4->3,34->4,17->5
            evs[w][k] = v0;
            evs[w + 4][k] = v1;
        }
        if (lane == 8) { evs[w][6] = q2A; evs[w + 4][6] = q2B; }
        if (lane == 4) { evs[w][7] = q1A; evs[w + 4][7] = q1B; }
    }
    __syncthreads();

    // ---- phase 4 (cooperative): wave w owns cols [256w, 256w+256) for
    //      ALL 8 rows; operands already in registers (prefetched).
    {
#pragma unroll
        for (int r = 0; r < 8; ++r) {
            const float4* ev4 = (const float4*)evs[r];
            float4 lo = ev4[0], hi = ev4[1];
            f32x2 E01 = { lo.x, lo.y }, E23 = { lo.z, lo.w };
            f32x2 E45 = { hi.x, hi.y }, E67 = { hi.z, hi.w };
            float res[4];
#pragma unroll
            for (int c = 0; c < 4; ++c) {
                f32x2 a2 = E01 * (f32x2){ wa[c].x, wa[c].y } + E23 * (f32x2){ wa[c].z, wa[c].w }
                         + E45 * (f32x2){ wb[c].x, wb[c].y } + E67 * (f32x2){ wb[c].z, wb[c].w };
                res[c] = a2.x + a2.y;
            }
            float4 o;
            o.x = bias.x + res[0]; o.y = bias.y + res[1];
            o.z = bias.z + res[2]; o.w = bias.w + res[3];
            ((float4*)(out + (size_t)(block8 + r) * 1024))[c4] = o;
        }
    }
}

extern "C" void kernel_launch(void* const* d_in, const int* in_sizes, int n_in,
                              void* d_out, int out_size, void* d_ws, size_t ws_size,
                              hipStream_t stream) {
    const float* x     = (const float*)d_in[0];
    const float* W_in  = (const float*)d_in[1];
    const float* b_in  = (const float*)d_in[2];
    const float* qw    = (const float*)d_in[3];
    const float* W_out = (const float*)d_in[4];
    const float* b_out = (const float*)d_in[5];
    float* outp = (float*)d_out;

    const int B = in_sizes[0] / 1024;   // 8192 rows
    const int grid = B / 8;             // 8 rows per 256-thread block
    qasa_kernel<<<grid, 256, 0, stream>>>(x, W_in, b_in, qw, W_out, b_out, outp);
}

// Round 7
// 102.523 us; speedup vs baseline: 1.0119x; 1.0119x over previous
//
#include <hip/hip_runtime.h>
#include <math.h>

// QASA layer: out = circuit(x @ W_in.T + b_in, q_weights) @ W_out.T + b_out
// 8 qubits -> 256 complex amps.
//
// Round 7: 32-LANE-ROW LAYOUT. Each wave holds TWO rows side-by-side:
// row A = lanes 0-31, row B = lanes 32-63. Within a half, state idx bits
// [7:3] = half-lane bits [4:0], idx bits [2:0] = 8 regs/lane (4 f32x2 re +
// 4 f32x2 im). Both rows ride ONE instruction stream (SIMT over halves):
// circuit issue halves vs round 6's 2x ggate calls. With 3 reg bits, 9 of
// 24 gates are register-local (vs 6) and the max cross-lane mask drops to
// 30: DS-pipe gates 12 -> 7 (masks 15/7 go to row_mirror/half_mirror DPP).
// DS ops/wave ~224 -> ~150 — attacks the per-CU LDS-pipe serialization
// that two neutral scheduling rounds isolated as the remaining bottleneck.
//
// Circuit algebra unchanged (CNOT ladders eliminated via F=I+S conjugation:
// gate on bit k after a ladders: RX axis = F^a e_k, RZ sign = row_k(F^-a),
// measurement absorbs F^-4; layer 0 + embedding absorbed into per-wire
// product factors). All 24 masks re-derived for the new bit mapping and
// cross-checked against the round-2-verified 64-lane table.

typedef float f32x2 __attribute__((ext_vector_type(2)));

__device__ __forceinline__ int f2i(float v) { return __float_as_int(v); }
__device__ __forceinline__ float i2f(int v) { return __int_as_float(v); }

template <int CTRL>
__device__ __forceinline__ float dppf(float v) {
    return i2f(__builtin_amdgcn_update_dpp(0, f2i(v), CTRL, 0xF, 0xF, true));
}

// xor-mask cross-lane: DPP (VALU pipe) for 1,2,3,7,8,15; ds_swizzle <32; shfl 32
template <int ML>
__device__ __forceinline__ float gshm(float v) {
    static_assert(ML > 0 && ML < 64, "lane mask");
    if constexpr (ML == 1)       return dppf<0xB1>(v);    // quad_perm [1,0,3,2]
    else if constexpr (ML == 2)  return dppf<0x4E>(v);    // quad_perm [2,3,0,1]
    else if constexpr (ML == 3)  return dppf<0x1B>(v);    // quad_perm [3,2,1,0]
    else if constexpr (ML == 7)  return dppf<0x141>(v);   // row_half_mirror = xor7
    else if constexpr (ML == 8)  return dppf<0x128>(v);   // row_ror:8 = xor8
    else if constexpr (ML == 15) return dppf<0x140>(v);   // row_mirror = xor15
    else if constexpr (ML < 32)  return i2f(__builtin_amdgcn_ds_swizzle(f2i(v), 0x1F | (ML << 10)));
    else                         return __shfl_xor(v, 32, 64);
}

template <int L>
__device__ __forceinline__ float rdlane(float v) {
    return i2f(__builtin_amdgcn_readlane(f2i(v), L));
}

__device__ __forceinline__ float bpermf(int addr, float v) {
    return i2f(__builtin_amdgcn_ds_bpermute(addr, f2i(v)));
}

// Generalized gate on 8-reg state: RX about axis (lane-mask ML, reg-mask MR),
// then RZ with sign = parity(lane&ZL) ^ parity(reg&ZR). reg r = 2j + comp.
template <int ML, int MR, int ZL, int ZR>
__device__ __forceinline__ void ggate8(f32x2 re[4], f32x2 im[4],
                                       float c1, float s1, float c2, float s2,
                                       int lane) {
    constexpr int JM = MR >> 1;
    constexpr bool CM = (MR & 1) != 0;
    f32x2 pRe[4], pIm[4];
#pragma unroll
    for (int j = 0; j < 4; ++j) {
        f32x2 sR = re[j ^ JM], sI = im[j ^ JM];
        if constexpr (CM) { sR = sR.yx; sI = sI.yx; }
        if constexpr (ML != 0) {
            pRe[j].x = gshm<ML>(sR.x); pRe[j].y = gshm<ML>(sR.y);
            pIm[j].x = gshm<ML>(sI.x); pIm[j].y = gshm<ML>(sI.y);
        } else { pRe[j] = sR; pIm[j] = sI; }
    }
    float base;
    if constexpr (ZL == 0) base = -s2;
    else                   base = (__popc(lane & ZL) & 1) ? s2 : -s2;
#pragma unroll
    for (int j = 0; j < 4; ++j) {
        f32x2 nR = c1 * re[j] + s1 * pIm[j];
        f32x2 nI = c1 * im[j] - s1 * pRe[j];
        const int pj = __builtin_popcount(j & (ZR >> 1)) & 1;  // folds post-unroll
        float sj = pj ? -base : base;
        float sc = (ZR & 1) ? -sj : sj;
        f32x2 ss = { sj, sc };
        re[j] = c2 * nR - ss * nI;
        im[j] = c2 * nI + ss * nR;
    }
}

__global__ void __launch_bounds__(256, 4) qasa_kernel(
    const float* __restrict__ x, const float* __restrict__ W_in,
    const float* __restrict__ b_in, const float* __restrict__ qw,
    const float* __restrict__ W_out, const float* __restrict__ b_out,
    float* __restrict__ out)
{
    const int tid = threadIdx.x;
    const int lane = tid & 63;
    const int w = tid >> 6;                       // wave id in block
    const int block8 = blockIdx.x * 8;

    __shared__ float ang[64];                     // [q][8 rows]
    __shared__ float evs[8][8] __attribute__((aligned(16)));  // [row][ev]

    // per-wave layer trig, lane-indexed in VGPRs (qw has exactly 64 entries)
    float vc, vs;
    __sincosf(0.5f * qw[lane], &vs, &vc);

    const int b0 = lane & 1, b1 = (lane >> 1) & 1, b3 = (lane >> 3) & 1;
    const int qofl = b0 | (b1 << 1) | (b3 << 2);  // qubit index pattern (bits 0,1,3)
    const float binq = b_in[qofl];

    // ---- phase 1 (cooperative, unchanged from round 6): wave w computes
    //      angles for q = 2w, 2w+1 over all 8 rows.
    {
        const float4* w4 = (const float4*)W_in;
        float4 wv0[4], wv1[4];
#pragma unroll
        for (int k = 0; k < 4; ++k) {
            wv0[k] = w4[(2 * w) * 256 + lane + 64 * k];
            wv1[k] = w4[(2 * w + 1) * 256 + lane + 64 * k];
        }
        const float4* xr0 = (const float4*)(x + (size_t)block8 * 1024);
        const float4* xr1 = (const float4*)(x + (size_t)(block8 + 4) * 1024);

        float4 xv[4][4];
#pragma unroll
        for (int r = 0; r < 4; ++r)
#pragma unroll
            for (int k = 0; k < 4; ++k)
                xv[r][k] = xr0[r * 256 + lane + 64 * k];

        f32x2 acc2[8];
#pragma unroll
        for (int j = 0; j < 8; ++j) acc2[j] = (f32x2){0.f, 0.f};
#pragma unroll
        for (int k = 0; k < 4; ++k)
#pragma unroll
            for (int r = 0; r < 4; ++r) {
                float4 xvv = xv[r][k];
                acc2[r]     += (f32x2){xvv.x, xvv.y} * (f32x2){wv0[k].x, wv0[k].y}
                             + (f32x2){xvv.z, xvv.w} * (f32x2){wv0[k].z, wv0[k].w};
                acc2[4 + r] += (f32x2){xvv.x, xvv.y} * (f32x2){wv1[k].x, wv1[k].y}
                             + (f32x2){xvv.z, xvv.w} * (f32x2){wv1[k].z, wv1[k].w};
            }

        float4 yv[4][4];
#pragma unroll
        for (int r = 0; r < 4; ++r)
#pragma unroll
            for (int k = 0; k < 4; ++k)
                yv[r][k] = xr1[r * 256 + lane + 64 * k];

        {
            float acc[8];
#pragma unroll
            for (int j = 0; j < 8; ++j) {
                acc[j] = acc2[j].x + acc2[j].y;
                acc[j] += dppf<0xB1>(acc[j]);
                acc[j] += dppf<0x4E>(acc[j]);
                acc[j] += dppf<0x128>(acc[j]);
            }
            float t01 = b0 ? acc[1] : acc[0];
            float t23 = b0 ? acc[3] : acc[2];
            float t45 = b0 ? acc[5] : acc[4];
            float t67 = b0 ? acc[7] : acc[6];
            float ta = b1 ? t23 : t01;
            float tb = b1 ? t67 : t45;
            float S = b3 ? tb : ta;
            S += gshm<4>(S); S += gshm<16>(S); S += gshm<32>(S);
            if ((lane & 52) == 0)
                ang[(2 * w + ((lane >> 3) & 1)) * 8 + (lane & 3)] = S;
        }
        {
            f32x2 bcc2[8];
#pragma unroll
            for (int j = 0; j < 8; ++j) bcc2[j] = (f32x2){0.f, 0.f};
#pragma unroll
            for (int k = 0; k < 4; ++k)
#pragma unroll
                for (int r = 0; r < 4; ++r) {
                    float4 xvv = yv[r][k];
                    bcc2[r]     += (f32x2){xvv.x, xvv.y} * (f32x2){wv0[k].x, wv0[k].y}
                                 + (f32x2){xvv.z, xvv.w} * (f32x2){wv0[k].z, wv0[k].w};
                    bcc2[4 + r] += (f32x2){xvv.x, xvv.y} * (f32x2){wv1[k].x, wv1[k].y}
                                 + (f32x2){xvv.z, xvv.w} * (f32x2){wv1[k].z, wv1[k].w};
                }
            float acc[8];
#pragma unroll
            for (int j = 0; j < 8; ++j) {
                acc[j] = bcc2[j].x + bcc2[j].y;
                acc[j] += dppf<0xB1>(acc[j]);
                acc[j] += dppf<0x4E>(acc[j]);
                acc[j] += dppf<0x128>(acc[j]);
            }
            float t01 = b0 ? acc[1] : acc[0];
            float t23 = b0 ? acc[3] : acc[2];
            float t45 = b0 ? acc[5] : acc[4];
            float t67 = b0 ? acc[7] : acc[6];
            float ta = b1 ? t23 : t01;
            float tb = b1 ? t67 : t45;
            float S = b3 ? tb : ta;
            S += gshm<4>(S); S += gshm<16>(S); S += gshm<32>(S);
            if ((lane & 52) == 0)
                ang[(2 * w + ((lane >> 3) & 1)) * 8 + 4 + (lane & 3)] = S;
        }
    }
    __syncthreads();

    // ---- phase-4 operand prefetch (latency hides under the circuit) ----
    const int c4 = (w << 6) + lane;
    const float4* wo = (const float4*)W_out;
    float4 wa[4], wb[4];
#pragma unroll
    for (int c = 0; c < 4; ++c) {
        wa[c] = wo[2 * (4 * c4 + c)];
        wb[c] = wo[2 * (4 * c4 + c) + 1];
    }
    float4 bias = ((const float4*)b_out)[c4];

    // ---- phase 2a: per-wire factor = RZ(qz) RX(qx) RZ(a) RX(a) |0> ----
    // Row of this lane = w + 4*half (half = lane bit 5). Publishing lanes
    // per half: l5 in {0..3,8..11} hold u-factor of qubit qofl; l5 in
    // {16..19,24..27} hold v-factor of the same qubit.
    const int half32 = lane & 32;
    const int rowsel = w + ((lane >> 3) & 4);
    const int isV = (lane >> 4) & 1;
    float A = ang[qofl * 8 + rowsel] + binq;
    float ca, sa;
    __sincosf(0.5f * A, &sa, &ca);
    float ur = ca * ca, ui = -ca * sa, vr = sa * sa, vi = ui;
    const int a1 = 4 * qofl, a2 = 4 * (qofl + 8);
    float cx = bpermf(a1, vc);
    float sx = bpermf(a1, vs);
    float cz = bpermf(a2, vc);
    float sz = bpermf(a2, vs);
    // RX(qx): u' = cx*u - i sx*v ; v' = cx*v - i sx*u
    float ur1 = cx * ur + sx * vi, ui1 = cx * ui - sx * vr;
    float vr1 = cx * vr + sx * ui, vi1 = cx * vi - sx * ur;
    // RZ(qz): u'' = (cz - i sz) u' ; v'' = (cz + i sz) v'
    float ur2 = cz * ur1 + sz * ui1, ui2 = cz * ui1 - sz * ur1;
    float vr2 = cz * vr1 - sz * vi1, vi2 = cz * vi1 + sz * vr1;
    const float fre = isV ? vr2 : ur2;
    const float fim = isV ? vi2 : ui2;

    // ---- phase 2b-init: product expansion (state after layer 0) ----
    // wires 0-4 -> half-lane bits 4..0 (factor lanes 0,1,2,3,8);
    // wires 5,6,7 -> reg bits 2,1,0 (factor lanes 9,10,11).
    float Pr, Pi;
    {
        int b = (lane >> 4) & 1;                       // wire0: l5 bit4
        int a = (half32 | (b << 4)) << 2;              // L=0
        Pr = bpermf(a, fre); Pi = bpermf(a, fim);
    }
#define PM(L_, SH_) { \
        int b = (lane >> (SH_)) & 1; \
        int a = (half32 + (L_) + (b << 4)) << 2; \
        float fr = bpermf(a, fre), fi = bpermf(a, fim); \
        float tr = Pr * fr - Pi * fi; \
        Pi = Pr * fi + Pi * fr; Pr = tr; }
    PM(1, 3) PM(2, 2) PM(3, 1) PM(8, 0)
#undef PM
    f32x2 re[4], im[4];
    {
        int a5u = (half32 + 9) << 2,  a5v = (half32 + 25) << 2;
        int a6u = (half32 + 10) << 2, a6v = (half32 + 26) << 2;
        int a7u = (half32 + 11) << 2, a7v = (half32 + 27) << 2;
        float u5r = bpermf(a5u, fre), u5i = bpermf(a5u, fim);
        float v5r = bpermf(a5v, fre), v5i = bpermf(a5v, fim);
        float u6r = bpermf(a6u, fre), u6i = bpermf(a6u, fim);
        float v6r = bpermf(a6v, fre), v6i = bpermf(a6v, fim);
        float u7r = bpermf(a7u, fre), u7i = bpermf(a7u, fim);
        float v7r = bpermf(a7v, fre), v7i = bpermf(a7v, fim);
        // h[b6<<1|b7] = f6 x f7
        float hr[4], hi[4];
        hr[0] = u6r * u7r - u6i * u7i;  hi[0] = u6r * u7i + u6i * u7r;
        hr[1] = u6r * v7r - u6i * v7i;  hi[1] = u6r * v7i + u6i * v7r;
        hr[2] = v6r * u7r - v6i * u7i;  hi[2] = v6r * u7i + v6i * u7r;
        hr[3] = v6r * v7r - v6i * v7i;  hi[3] = v6r * v7i + v6i * v7r;
        float rr[8], ii[8];
#pragma unroll
        for (int r = 0; r < 8; ++r) {
            float f5r = (r & 4) ? v5r : u5r, f5i = (r & 4) ? v5i : u5i;
            float gr = f5r * hr[r & 3] - f5i * hi[r & 3];
            float gi = f5r * hi[r & 3] + f5i * hr[r & 3];
            rr[r] = Pr * gr - Pi * gi;
            ii[r] = Pr * gi + Pi * gr;
        }
#pragma unroll
        for (int j = 0; j < 4; ++j) {
            re[j] = (f32x2){ rr[2 * j], rr[2 * j + 1] };
            im[j] = (f32x2){ ii[2 * j], ii[2 * j + 1] };
        }
    }

    // ---- phase 2b: layers 2-4, one SIMT stream covers both rows ----
    // qw[l][0][i] -> lane 16l+i (RX), qw[l][1][i] -> lane 16l+8+i (RZ)
#define GG(Lx, W_, ML_, MR_, ZL_, ZR_) { \
    float c1 = rdlane<16 * (Lx) + (W_)>(vc), s1 = rdlane<16 * (Lx) + (W_)>(vs); \
    float c2 = rdlane<16 * (Lx) + 8 + (W_)>(vc), s2 = rdlane<16 * (Lx) + 8 + (W_)>(vs); \
    ggate8<ML_, MR_, ZL_, ZR_>(re, im, c1, s1, c2, s2, lane); }

    // layer 2 (a=1): axis {k,k-1}; RZ rows {k..7}
    GG(1,0, 24,0, 16,0)  GG(1,1, 12,0, 24,0)  GG(1,2, 6,0, 28,0)  GG(1,3, 3,0, 30,0)
    GG(1,4, 1,4, 31,0)   GG(1,5, 0,6, 31,4)   GG(1,6, 0,3, 31,6)  GG(1,7, 0,1, 31,7)
    // layer 3 (a=2): axis {k,k-2}; RZ rows {k,k+2,k+4,k+6}
    GG(2,0, 20,0, 16,0)  GG(2,1, 10,0, 8,0)   GG(2,2, 5,0, 20,0)  GG(2,3, 2,4, 10,0)
    GG(2,4, 1,2, 21,0)   GG(2,5, 0,5, 10,4)   GG(2,6, 0,2, 21,2)  GG(2,7, 0,1, 10,5)
    // layer 4 (a=3): axis {k..k-3}; RZ rows {k,k+1,k+4,k+5}
    GG(3,0, 30,0, 16,0)  GG(3,1, 15,0, 24,0)  GG(3,2, 7,4, 12,0)  GG(3,3, 3,6, 6,0)
    GG(3,4, 1,7, 19,0)   GG(3,5, 0,7, 25,4)   GG(3,6, 0,3, 12,6)  GG(3,7, 0,1, 6,3)
#undef GG

    // ---- phase 3: expvals (F^-4 masks row_k = {k,k+4}), per 32-lane half ----
    // EV0..EV3: q0-coeff at lane masks 16,8,4,2; EV4: q0@17;
    // EV5: q4@8; EV6: q2@4; EV7: q1@2 (reg-mask sums, signed lane stage).
    {
        f32x2 pp0 = re[0] * re[0] + im[0] * im[0];
        f32x2 pp1 = re[1] * re[1] + im[1] * im[1];
        f32x2 pp2 = re[2] * re[2] + im[2] * im[2];
        f32x2 pp3 = re[3] * re[3] + im[3] * im[3];
        float sx0 = pp0.x + pp0.y, dx0 = pp0.x - pp0.y;
        float sx1 = pp1.x + pp1.y, dx1 = pp1.x - pp1.y;
        float sx2 = pp2.x + pp2.y, dx2 = pp2.x - pp2.y;
        float sx3 = pp3.x + pp3.y, dx3 = pp3.x - pp3.y;
        float q0 = (sx0 + sx1) + (sx2 + sx3);          // reg-mask 0
        float q1 = (dx0 + dx1) + (dx2 + dx3);          // reg-mask 1 (r bit0)
        float q2 = (sx0 - sx1) + (sx2 - sx3);          // reg-mask 2 (r bit1)
        float q4 = (sx0 + sx1) - (sx2 + sx3);          // reg-mask 4 (r bit2)

        // q0: full signed Walsh over half-lane bits 0..4
        { float u = dppf<0xB1>(q0);  q0 = (lane & 1)  ? (u - q0) : (q0 + u); }
        { float u = dppf<0x4E>(q0);  q0 = (lane & 2)  ? (u - q0) : (q0 + u); }
        { float u = gshm<4>(q0);     q0 = (lane & 4)  ? (u - q0) : (q0 + u); }
        { float u = dppf<0x128>(q0); q0 = (lane & 8)  ? (u - q0) : (q0 + u); }
        { float u = gshm<16>(q0);    q0 = (lane & 16) ? (u - q0) : (q0 + u); }
        // q4: signed at bit3 only
        q4 += dppf<0xB1>(q4); q4 += dppf<0x4E>(q4); q4 += gshm<4>(q4);
        { float u = dppf<0x128>(q4); q4 = (lane & 8) ? (u - q4) : (q4 + u); }
        q4 += gshm<16>(q4);
        // q2: signed at bit2 only
        q2 += dppf<0xB1>(q2); q2 += dppf<0x4E>(q2);
        { float u = gshm<4>(q2); q2 = (lane & 4) ? (u - q2) : (q2 + u); }
        q2 += dppf<0x128>(q2); q2 += gshm<16>(q2);
        // q1: signed at bit1 only
        q1 += dppf<0xB1>(q1);
        { float u = dppf<0x4E>(q1); q1 = (lane & 2) ? (u - q1) : (q1 + u); }
        q1 += gshm<4>(q1); q1 += dppf<0x128>(q1); q1 += gshm<16>(q1);

        const int l5 = lane & 31;
        const int row = rowsel;
        if (l5 == 16)      { evs[row][0] = q0; }
        else if (l5 == 8)  { evs[row][1] = q0; evs[row][5] = q4; }
        else if (l5 == 4)  { evs[row][2] = q0; evs[row][6] = q2; }
        else if (l5 == 2)  { evs[row][3] = q0; evs[row][7] = q1; }
        else if (l5 == 17) { evs[row][4] = q0; }
    }
    __syncthreads();

    // ---- phase 4 (cooperative, unchanged): wave w owns cols [256w,256w+256)
    //      for all 8 rows; operands already in registers.
    {
#pragma unroll
        for (int r = 0; r < 8; ++r) {
            const float4* ev4 = (const float4*)evs[r];
            float4 lo = ev4[0], hi = ev4[1];
            f32x2 E01 = { lo.x, lo.y }, E23 = { lo.z, lo.w };
            f32x2 E45 = { hi.x, hi.y }, E67 = { hi.z, hi.w };
            float res[4];
#pragma unroll
            for (int c = 0; c < 4; ++c) {
                f32x2 a2v = E01 * (f32x2){ wa[c].x, wa[c].y } + E23 * (f32x2){ wa[c].z, wa[c].w }
                          + E45 * (f32x2){ wb[c].x, wb[c].y } + E67 * (f32x2){ wb[c].z, wb[c].w };
                res[c] = a2v.x + a2v.y;
            }
            float4 o;
            o.x = bias.x + res[0]; o.y = bias.y + res[1];
            o.z = bias.z + res[2]; o.w = bias.w + res[3];
            ((float4*)(out + (size_t)(block8 + r) * 1024))[c4] = o;
        }
    }
}

extern "C" void kernel_launch(void* const* d_in, const int* in_sizes, int n_in,
                              void* d_out, int out_size, void* d_ws, size_t ws_size,
                              hipStream_t stream) {
    const float* x     = (const float*)d_in[0];
    const float* W_in  = (const float*)d_in[1];
    const float* b_in  = (const float*)d_in[2];
    const float* qw    = (const float*)d_in[3];
    const float* W_out = (const float*)d_in[4];
    const float* b_out = (const float*)d_in[5];
    float* outp = (float*)d_out;

    const int B = in_sizes[0] / 1024;   // 8192 rows
    const int grid = B / 8;             // 8 rows per 256-thread block
    qasa_kernel<<<grid, 256, 0, stream>>>(x, W_in, b_in, qw, W_out, b_out, outp);
}